// Round 4
// baseline (1483.513 us; speedup 1.0000x reference)
//
#include <hip/hip_runtime.h>
#include <stdint.h>

typedef __bf16 bf16;
typedef __bf16 bf16x8 __attribute__((ext_vector_type(8)));
typedef float f32x4 __attribute__((ext_vector_type(4)));

using gp_t = __attribute__((address_space(1))) const void*;
using lp_t = __attribute__((address_space(3))) void*;

__device__ __forceinline__ void gld16(const void* g, void* l) {
  __builtin_amdgcn_global_load_lds((gp_t)g, (lp_t)l, 16, 0, 0);
}

// Runtime dtype detection: read 64 u32 words of hidden_states (same words in
// every wave).  Packed bf16 pairs ~N(0,1): bits14..7 = low element's exponent
// in [112,130].  fp32: bits14..7 are mantissa bits, ~uniform(0..255).
// P(fp32 passes all 64) ~ 0.16^64 ~ 1e-51.  Wave-uniform result.
__device__ __forceinline__ bool detect_fp32(const uint32_t* det) {
  uint32_t w = det[threadIdx.x & 63];
  int e = (w >> 7) & 0xFF;
  bool bf_ok = (e >= 100) && (e <= 140);
  return __ballot(bf_ok) != ~0ULL;
}

// ---------------------------------------------------------------------------
// C[M,N] = A[M,K] @ W[N,K]^T + bias[N]   (fp32 acc, dual-dtype operands)
//   a_follows: A dtype follows detected input dtype (else A is bf16)
//   W/bias always follow detected input dtype (they are harness inputs)
//   store_sel: 0 = bf16 row-major, 1 = bf16 V^T-transposed, 2 = final output
//              (dtype follows detected input dtype)
// 128x128 tile, BK=64, XOR-swizzled LDS; bf16 path uses global_load_lds w=16,
// fp32 path stages via float4 loads + cvt + ds_write_b128.
// ---------------------------------------------------------------------------
__global__ __launch_bounds__(256, 2)
void gemm_bt(const void* __restrict__ A, const void* __restrict__ W,
             const void* __restrict__ bias, void* __restrict__ C,
             int M, int N, int K, int a_follows, int store_sel,
             const uint32_t* __restrict__ det)
{
  __shared__ __align__(16) bf16 As[128 * 64];
  __shared__ __align__(16) bf16 Bs[128 * 64];
  const int tid  = threadIdx.x;
  const int lane = tid & 63;
  const int w    = tid >> 6;
  const int wm   = w >> 1, wn = w & 1;
  const int quad = lane >> 4, l16 = lane & 15;
  const int m0 = blockIdx.x * 128, n0 = blockIdx.y * 128;

  const bool fp32_in = detect_fp32(det);
  const bool a_fp32  = fp32_in && (a_follows != 0);

  f32x4 acc[4][4] = {};

  for (int k0 = 0; k0 < K; k0 += 64) {
#pragma unroll
    for (int it = 0; it < 4; it++) {
      int c = tid + it * 256;          // lane-contiguous LDS slots (required)
      int row = c >> 3;
      int cc  = (c & 7) ^ (row & 7);   // XOR swizzle on 16B chunks
      size_t goff = (size_t)(m0 + row) * K + k0 + cc * 8;
      if (!a_fp32) {
        gld16((const bf16*)A + goff, &As[c * 8]);
      } else {
        const float* Af = (const float*)A;
        float4 x0 = *(const float4*)(Af + goff);
        float4 x1 = *(const float4*)(Af + goff + 4);
        bf16x8 v;
        v[0] = (bf16)x0.x; v[1] = (bf16)x0.y; v[2] = (bf16)x0.z; v[3] = (bf16)x0.w;
        v[4] = (bf16)x1.x; v[5] = (bf16)x1.y; v[6] = (bf16)x1.z; v[7] = (bf16)x1.w;
        *(bf16x8*)&As[c * 8] = v;
      }
      size_t woff = (size_t)(n0 + row) * K + k0 + cc * 8;
      if (!fp32_in) {
        gld16((const bf16*)W + woff, &Bs[c * 8]);
      } else {
        const float* Wf = (const float*)W;
        float4 x0 = *(const float4*)(Wf + woff);
        float4 x1 = *(const float4*)(Wf + woff + 4);
        bf16x8 v;
        v[0] = (bf16)x0.x; v[1] = (bf16)x0.y; v[2] = (bf16)x0.z; v[3] = (bf16)x0.w;
        v[4] = (bf16)x1.x; v[5] = (bf16)x1.y; v[6] = (bf16)x1.z; v[7] = (bf16)x1.w;
        *(bf16x8*)&Bs[c * 8] = v;
      }
    }
    __syncthreads();                   // drains vmcnt (gld16) + lgkmcnt (ds_write)
#pragma unroll
    for (int dk = 0; dk < 2; dk++) {
      bf16x8 af[4], bw[4];
#pragma unroll
      for (int i = 0; i < 4; i++) {
        int row = wm * 64 + i * 16 + l16;
        af[i] = *(const bf16x8*)&As[(row * 8 + ((dk * 4 + quad) ^ (row & 7))) * 8];
      }
#pragma unroll
      for (int j = 0; j < 4; j++) {
        int row = wn * 64 + j * 16 + l16;
        bw[j] = *(const bf16x8*)&Bs[(row * 8 + ((dk * 4 + quad) ^ (row & 7))) * 8];
      }
#pragma unroll
      for (int i = 0; i < 4; i++)
#pragma unroll
        for (int j = 0; j < 4; j++)
          acc[i][j] = __builtin_amdgcn_mfma_f32_16x16x32_bf16(af[i], bw[j], acc[i][j], 0, 0, 0);
    }
    __syncthreads();
  }

  // epilogue: C/D layout col=lane&15, row=quad*4+reg (m89/m91-verified)
#pragma unroll
  for (int j = 0; j < 4; j++) {
    int col = n0 + wn * 64 + j * 16 + l16;
    float bv = fp32_in ? ((const float*)bias)[col] : (float)((const bf16*)bias)[col];
#pragma unroll
    for (int i = 0; i < 4; i++) {
#pragma unroll
      for (int r = 0; r < 4; r++) {
        int row = m0 + wm * 64 + i * 16 + quad * 4 + r;
        float v = acc[i][j][r] + bv;
        if (store_sel == 0) {
          ((bf16*)C)[(size_t)row * N + col] = (bf16)v;
        } else if (store_sel == 1) {
          int b = row >> 11, s = row & 2047;   // S=2048 per batch
          ((bf16*)C)[((size_t)(b * 128 + col)) * 2048 + s] = (bf16)v;
        } else {
          if (fp32_in) ((float*)C)[(size_t)row * N + col] = v;
          else         ((bf16*)C)[(size_t)row * N + col] = (bf16)v;
        }
      }
    }
  }
}

// ---------------------------------------------------------------------------
// Causal MQA flash attention (all-bf16 intermediates — dtype-independent).
// grid = (qi=16, bh=64), block = 256 (4 waves).  BQ=128, k-tiles of 64.
// AO may ALIAS Qg in place (block writes exactly the Q region only it reads;
// Q is register-resident before any epilogue store).
// LDS: KPs = K-tile (64x128) aliased with P (128x64), Vs = V^T tile, ~35 KB.
// ---------------------------------------------------------------------------
__global__ __launch_bounds__(256, 2)
void mqa_attn(const bf16* Qg, const bf16* __restrict__ Kg,
              const bf16* __restrict__ Vtg, bf16* AO)
{
  __shared__ __align__(16) bf16 KPs[64 * 128];
  __shared__ __align__(16) bf16 Vs[128 * 64];
  __shared__ float m_state[128], l_state[128];
  __shared__ float wmax[2][128], wsum[2][128];

  const int tid  = threadIdx.x;
  const int lane = tid & 63;
  const int w    = tid >> 6;
  const int wm   = w >> 1, wn = w & 1;
  const int quad = lane >> 4, l16 = lane & 15;
  const int qi = blockIdx.x;
  const int bh = blockIdx.y;
  const int b  = bh >> 4, h = bh & 15;
  const int q0 = qi * 128;
  const float scale = 0.08838834764831845f;   // 1/sqrt(128)
  const float NEG = -3.0e4f;                  // finite mask value, exp -> 0

  // Q fragments in registers (A-operand layout: m=lane&15, k=quad*8+j)
  bf16x8 aq[4][4];
  {
    const bf16* qb = Qg + ((size_t)(b * 2048 + q0 + wm * 64 + l16)) * 2048 + h * 128 + quad * 8;
#pragma unroll
    for (int i = 0; i < 4; i++)
#pragma unroll
      for (int dk = 0; dk < 4; dk++)
        aq[i][dk] = *(const bf16x8*)(qb + (size_t)i * 16 * 2048 + dk * 32);
  }

  if (tid < 128) { m_state[tid] = NEG; l_state[tid] = 0.0f; }
  __syncthreads();

  f32x4 o[4][4] = {};

  const int ntiles = 2 * qi + 2;
  for (int kt = 0; kt < ntiles; kt++) {
    const int kk0 = kt * 64;
#pragma unroll
    for (int it = 0; it < 4; it++) {
      int c = tid + it * 256;
      int rk = c >> 4, ck = (c & 15) ^ (rk & 15);
      gld16(Kg + ((size_t)(b * 2048 + kk0 + rk)) * 128 + ck * 8, &KPs[c * 8]);
      int rv = c >> 3, cv = (c & 7) ^ (rv & 7);
      gld16(Vtg + ((size_t)(b * 128 + rv)) * 2048 + kk0 + cv * 8, &Vs[c * 8]);
    }
    __syncthreads();   // B_a: staging visible

    // S = Q K^T : per-wave 64q x 32kk
    f32x4 s[4][2] = {};
#pragma unroll
    for (int dk = 0; dk < 4; dk++) {
      bf16x8 bk[2];
#pragma unroll
      for (int j = 0; j < 2; j++) {
        int row = wn * 32 + j * 16 + l16;
        bk[j] = *(const bf16x8*)&KPs[(row * 16 + ((dk * 4 + quad) ^ (row & 15))) * 8];
      }
#pragma unroll
      for (int i = 0; i < 4; i++)
#pragma unroll
        for (int j = 0; j < 2; j++)
          s[i][j] = __builtin_amdgcn_mfma_f32_16x16x32_bf16(aq[i][dk], bk[j], s[i][j], 0, 0, 0);
    }

    const bool masked_tile = (kk0 + 63 > q0);
#pragma unroll
    for (int i = 0; i < 4; i++)
#pragma unroll
      for (int j = 0; j < 2; j++)
#pragma unroll
        for (int r = 0; r < 4; r++) {
          float v = s[i][j][r] * scale;
          if (masked_tile) {
            int rg = q0 + wm * 64 + i * 16 + quad * 4 + r;
            int cg = kk0 + wn * 32 + j * 16 + l16;
            if (cg > rg) v = NEG;
          }
          s[i][j][r] = v;
        }

#pragma unroll
    for (int i = 0; i < 4; i++)
#pragma unroll
      for (int r = 0; r < 4; r++) {
        float mx = fmaxf(s[i][0][r], s[i][1][r]);
#pragma unroll
        for (int t = 1; t < 16; t <<= 1) mx = fmaxf(mx, __shfl_xor(mx, t, 64));
        if (l16 == 0) wmax[wn][wm * 64 + i * 16 + quad * 4 + r] = mx;
      }
    __syncthreads();   // B_b: wmax visible; K-tile reads done (P may overwrite)

#pragma unroll
    for (int i = 0; i < 4; i++)
#pragma unroll
      for (int r = 0; r < 4; r++) {
        int row = wm * 64 + i * 16 + quad * 4 + r;
        float mo = m_state[row];
        float mn = fmaxf(mo, fmaxf(wmax[0][row], wmax[1][row]));
        float alpha = __expf(mo - mn);
        float rs = 0.0f;
#pragma unroll
        for (int j = 0; j < 2; j++) {
          float p = __expf(s[i][j][r] - mn);
          rs += p;
          int col = wn * 32 + j * 16 + l16;
          KPs[((row << 3) + ((col >> 3) ^ (row & 7))) * 8 + (col & 7)] = (bf16)p;
        }
#pragma unroll
        for (int t = 1; t < 16; t <<= 1) rs += __shfl_xor(rs, t, 64);
        if (l16 == 0) wsum[wn][row] = rs;
#pragma unroll
        for (int j = 0; j < 4; j++) o[i][j][r] *= alpha;
      }
    __syncthreads();   // B_c: P + wsum visible

    if (tid < 128) {
      float mo = m_state[tid];
      float mn = fmaxf(mo, fmaxf(wmax[0][tid], wmax[1][tid]));
      l_state[tid] = l_state[tid] * __expf(mo - mn) + wsum[0][tid] + wsum[1][tid];
      m_state[tid] = mn;
    }

#pragma unroll
    for (int kkt = 0; kkt < 2; kkt++) {
      bf16x8 ap[4], bv[4];
#pragma unroll
      for (int i = 0; i < 4; i++) {
        int row = wm * 64 + i * 16 + l16;
        ap[i] = *(const bf16x8*)&KPs[((row << 3) + ((kkt * 4 + quad) ^ (row & 7))) * 8];
      }
#pragma unroll
      for (int j = 0; j < 4; j++) {
        int row = wn * 64 + j * 16 + l16;
        bv[j] = *(const bf16x8*)&Vs[((row << 3) + ((kkt * 4 + quad) ^ (row & 7))) * 8];
      }
#pragma unroll
      for (int i = 0; i < 4; i++)
#pragma unroll
        for (int j = 0; j < 4; j++)
          o[i][j] = __builtin_amdgcn_mfma_f32_16x16x32_bf16(ap[i], bv[j], o[i][j], 0, 0, 0);
    }
    __syncthreads();   // B_d: PV done; state update visible; safe to restage
  }

#pragma unroll
  for (int i = 0; i < 4; i++)
#pragma unroll
    for (int r = 0; r < 4; r++) {
      int row = wm * 64 + i * 16 + quad * 4 + r;
      float l = l_state[row];
      float inv = (l > 0.0f) ? 1.0f / l : 0.0f;
      size_t base = ((size_t)(b * 2048 + q0 + row)) * 2048 + h * 128;
#pragma unroll
      for (int j = 0; j < 4; j++) {
        int col = wn * 64 + j * 16 + l16;
        AO[base + col] = (bf16)(o[i][j][r] * inv);
      }
    }
}

// ---------------------------------------------------------------------------
// Memory plan (d_ws usage = 32 MB; d_out >= 32 MB bytes in either dtype):
//   Qg  = ws + 0        (32 MB)  Q bf16 (b,s,h,d); AO overwrites in place
//   Kg  = d_out + 0     ( 2 MB)  K bf16 (b,s,d)   — d_out dead until O-proj
//   Vtg = d_out + 2 MB  ( 2 MB)  V^T bf16 (b,d,s)
// All projection intermediates forced bf16; input/output dtype is detected at
// runtime inside each GEMM (fp32 vs bf16 — see detect_fp32).
// ---------------------------------------------------------------------------
extern "C" void kernel_launch(void* const* d_in, const int* in_sizes, int n_in,
                              void* d_out, int out_size, void* d_ws, size_t ws_size,
                              hipStream_t stream)
{
  const void* X   = d_in[0];
  const void* q_w = d_in[1];
  const void* q_b = d_in[2];
  const void* k_w = d_in[3];
  const void* k_b = d_in[4];
  const void* v_w = d_in[5];
  const void* v_b = d_in[6];
  const void* o_w = d_in[7];
  const void* o_b = d_in[8];
  const uint32_t* det = (const uint32_t*)X;

  bf16* Qg  = (bf16*)d_ws;                       // 8192 x 2048 (b,s,h,d)
  bf16* AO  = Qg;                                // in-place (see mqa_attn)
  bf16* Kg  = (bf16*)d_out;                      // 8192 x 128  (b,s,d)
  bf16* Vtg = (bf16*)((char*)d_out + 2097152);   // 4 x 128 x 2048 V^T (b,d,s)

  dim3 blk(256);
  //                                      A  W    b    C    M     N     K   aF sS det
  gemm_bt<<<dim3(64, 16), blk, 0, stream>>>(X, q_w, q_b, Qg,  8192, 2048, 2048, 1, 0, det);
  gemm_bt<<<dim3(64, 1),  blk, 0, stream>>>(X, k_w, k_b, Kg,  8192, 128,  2048, 1, 0, det);
  gemm_bt<<<dim3(64, 1),  blk, 0, stream>>>(X, v_w, v_b, Vtg, 8192, 128,  2048, 1, 1, det);
  mqa_attn<<<dim3(16, 64), blk, 0, stream>>>(Qg, Kg, Vtg, AO);
  gemm_bt<<<dim3(64, 16), blk, 0, stream>>>(AO, o_w, o_b, d_out, 8192, 2048, 2048, 0, 2, det);
}

// Round 5
// 641.488 us; speedup vs baseline: 2.3126x; 2.3126x over previous
//
#include <hip/hip_runtime.h>
#include <stdint.h>

typedef __bf16 bf16;
typedef __bf16 bf16x4 __attribute__((ext_vector_type(4)));
typedef __bf16 bf16x8 __attribute__((ext_vector_type(8)));
typedef float f32x4 __attribute__((ext_vector_type(4)));

using gp_t = __attribute__((address_space(1))) const void*;
using lp_t = __attribute__((address_space(3))) void*;

__device__ __forceinline__ void gld16(const void* g, void* l) {
  __builtin_amdgcn_global_load_lds((gp_t)g, (lp_t)l, 16, 0, 0);
}

// ---------------------------------------------------------------------------
// fp32 -> bf16 conversion, segment table (one kernel, grid-stride per segment)
// ---------------------------------------------------------------------------
struct CvtSegs {
  const float* src[10];
  bf16* dst[10];
  int cnt[10];     // element counts, divisible by 4
  int n;
};

__global__ void cvt_kernel(CvtSegs segs) {
  const int stride = gridDim.x * blockDim.x;
  const int t0 = blockIdx.x * blockDim.x + threadIdx.x;
  for (int s = 0; s < segs.n; s++) {
    const float4* src = (const float4*)segs.src[s];
    bf16x4* dst = (bf16x4*)segs.dst[s];
    int cnt4 = segs.cnt[s] >> 2;
    for (int idx = t0; idx < cnt4; idx += stride) {
      float4 v = src[idx];
      bf16x4 o; o[0] = (bf16)v.x; o[1] = (bf16)v.y; o[2] = (bf16)v.z; o[3] = (bf16)v.w;
      dst[idx] = o;
    }
  }
}

// ---------------------------------------------------------------------------
// C[M,N] = A[M,K] @ W[N,K]^T + bias[N]   (bf16 A via global_load_lds;
// W bf16 fast path or fp32 float4+cvt fallback).  128x128 tile, BK=64,
// XOR-swizzled LDS, m97-style 2-barrier K-loop.
// store_sel: 0 = bf16 row-major C
//            2 = fp32 row-major C (final output)
//            3 = fused KV: col<128 -> K row-major (b,s,d) at C;
//                          col>=128 -> V^T (b,d,s) at C + 1048576 elements
// ---------------------------------------------------------------------------
__global__ __launch_bounds__(256, 2)
void gemm_bt(const bf16* __restrict__ A, const void* __restrict__ Wv,
             const void* __restrict__ biasv, void* __restrict__ Cv,
             int M, int N, int K, int w_fp32, int bias_fp32, int store_sel)
{
  __shared__ __align__(16) bf16 As[128 * 64];
  __shared__ __align__(16) bf16 Bs[128 * 64];
  const int tid  = threadIdx.x;
  const int lane = tid & 63;
  const int w    = tid >> 6;
  const int wm   = w >> 1, wn = w & 1;
  const int quad = lane >> 4, l16 = lane & 15;
  const int m0 = blockIdx.x * 128, n0 = blockIdx.y * 128;

  f32x4 acc[4][4] = {};

  for (int k0 = 0; k0 < K; k0 += 64) {
#pragma unroll
    for (int it = 0; it < 4; it++) {
      int c = tid + it * 256;          // lane-contiguous LDS slots (required)
      int row = c >> 3;
      int cc  = (c & 7) ^ (row & 7);   // XOR swizzle on 16B chunks
      gld16(A + (size_t)(m0 + row) * K + k0 + cc * 8, &As[c * 8]);
      size_t woff = (size_t)(n0 + row) * K + k0 + cc * 8;
      if (!w_fp32) {
        gld16((const bf16*)Wv + woff, &Bs[c * 8]);
      } else {
        const float* Wf = (const float*)Wv;
        float4 x0 = *(const float4*)(Wf + woff);
        float4 x1 = *(const float4*)(Wf + woff + 4);
        bf16x8 v;
        v[0] = (bf16)x0.x; v[1] = (bf16)x0.y; v[2] = (bf16)x0.z; v[3] = (bf16)x0.w;
        v[4] = (bf16)x1.x; v[5] = (bf16)x1.y; v[6] = (bf16)x1.z; v[7] = (bf16)x1.w;
        *(bf16x8*)&Bs[c * 8] = v;
      }
    }
    __syncthreads();                   // drains vmcnt (gld16) + lgkmcnt
#pragma unroll
    for (int dk = 0; dk < 2; dk++) {
      bf16x8 af[4], bw[4];
#pragma unroll
      for (int i = 0; i < 4; i++) {
        int row = wm * 64 + i * 16 + l16;
        af[i] = *(const bf16x8*)&As[(row * 8 + ((dk * 4 + quad) ^ (row & 7))) * 8];
      }
#pragma unroll
      for (int j = 0; j < 4; j++) {
        int row = wn * 64 + j * 16 + l16;
        bw[j] = *(const bf16x8*)&Bs[(row * 8 + ((dk * 4 + quad) ^ (row & 7))) * 8];
      }
#pragma unroll
      for (int i = 0; i < 4; i++)
#pragma unroll
        for (int j = 0; j < 4; j++)
          acc[i][j] = __builtin_amdgcn_mfma_f32_16x16x32_bf16(af[i], bw[j], acc[i][j], 0, 0, 0);
    }
    __syncthreads();
  }

  // epilogue: C/D layout col=lane&15, row=quad*4+reg (m89/m91-verified)
#pragma unroll
  for (int j = 0; j < 4; j++) {
    int col = n0 + wn * 64 + j * 16 + l16;
    float bv = bias_fp32 ? ((const float*)biasv)[col] : (float)((const bf16*)biasv)[col];
#pragma unroll
    for (int i = 0; i < 4; i++) {
#pragma unroll
      for (int r = 0; r < 4; r++) {
        int row = m0 + wm * 64 + i * 16 + quad * 4 + r;
        float v = acc[i][j][r] + bv;
        if (store_sel == 0) {
          ((bf16*)Cv)[(size_t)row * N + col] = (bf16)v;
        } else if (store_sel == 2) {
          ((float*)Cv)[(size_t)row * N + col] = v;
        } else {   // fused KV split
          int b = row >> 11, s = row & 2047;   // S=2048 per batch
          if (col < 128) {
            ((bf16*)Cv)[(size_t)row * 128 + col] = (bf16)v;              // K (b,s,d)
          } else {
            ((bf16*)Cv + 1048576)[((size_t)(b * 128 + (col - 128))) * 2048 + s] = (bf16)v; // V^T
          }
        }
      }
    }
  }
}

// ---------------------------------------------------------------------------
// Causal MQA flash attention, wave-private softmax.
// grid = (qi=16, bh=64), block = 256 (4 waves).  BQ=128: wave w owns q-rows
// w*32..w*32+31 and the FULL 64-key tile -> softmax is wave-local (register
// m/l state, in-wave shuffles, private P region; no cross-wave exchange).
// Barriers: 2 per k-tile (after cooperative K/V stage; before restage).
// AO may ALIAS Qg in place (block writes exactly the Q region only it reads;
// Q is register-resident before any epilogue store).
// LDS: Ks 16 KB + Vs 16 KB + Ps 4x(32x64) 16 KB = 48 KB.
// ---------------------------------------------------------------------------
__global__ __launch_bounds__(256, 2)
void mqa_attn(const bf16* Qg, const bf16* __restrict__ Kg,
              const bf16* __restrict__ Vtg, bf16* AO)
{
  __shared__ __align__(16) bf16 Ks[64 * 128];
  __shared__ __align__(16) bf16 Vs[128 * 64];
  __shared__ __align__(16) bf16 Ps[4 * 32 * 64];

  const int tid  = threadIdx.x;
  const int lane = tid & 63;
  const int w    = tid >> 6;
  const int quad = lane >> 4, l16 = lane & 15;
  const int rb   = w * 32;              // wave's q-row base within tile
  const int pbase = w * 2048;           // wave's private P region (32x64)
  const int qi = blockIdx.x;
  const int bh = blockIdx.y;
  const int b  = bh >> 4, h = bh & 15;
  const int q0 = qi * 128;
  const float scale = 0.08838834764831845f;   // 1/sqrt(128)
  const float NEG = -3.0e4f;                  // finite mask value, exp -> 0

  // Q fragments (A-operand: m=l16, k=quad*8+e, dk selects k-32-group)
  bf16x8 aq[2][4];
  {
    const bf16* qb = Qg + ((size_t)(b * 2048 + q0 + rb + l16)) * 2048 + h * 128 + quad * 8;
#pragma unroll
    for (int i = 0; i < 2; i++)
#pragma unroll
      for (int dk = 0; dk < 4; dk++)
        aq[i][dk] = *(const bf16x8*)(qb + (size_t)i * 16 * 2048 + dk * 32);
  }

  float m_reg[2][4], l_reg[2][4];
#pragma unroll
  for (int i = 0; i < 2; i++)
#pragma unroll
    for (int r = 0; r < 4; r++) { m_reg[i][r] = NEG; l_reg[i][r] = 0.0f; }

  f32x4 o[2][8] = {};   // rows i*16+quad*4+r, d-cols j*16+l16

  const int ntiles = 2 * qi + 2;
  for (int kt = 0; kt < ntiles; kt++) {
    const int kk0 = kt * 64;
    // cooperative stage: K (64x128) and V^T (128x64), XOR-swizzled chunks
#pragma unroll
    for (int it = 0; it < 4; it++) {
      int c = tid + it * 256;
      int rk = c >> 4, ck = (c & 15) ^ (rk & 15);
      gld16(Kg + ((size_t)(b * 2048 + kk0 + rk)) * 128 + ck * 8, &Ks[c * 8]);
      int rv = c >> 3, cv = (c & 7) ^ (rv & 7);
      gld16(Vtg + ((size_t)(b * 128 + rv)) * 2048 + kk0 + cv * 8, &Vs[c * 8]);
    }
    __syncthreads();   // B1: staging visible

    if (kk0 <= q0 + rb + 31) {   // wave-uniform: skip fully-masked tiles
      // S = Q K^T : 32 q-rows x 64 keys per wave
      f32x4 s[2][4] = {};
#pragma unroll
      for (int dk = 0; dk < 4; dk++) {
        bf16x8 bk[4];
#pragma unroll
        for (int j = 0; j < 4; j++) {
          int row = j * 16 + l16;   // key index
          bk[j] = *(const bf16x8*)&Ks[(row * 16 + ((dk * 4 + quad) ^ (row & 15))) * 8];
        }
#pragma unroll
        for (int i = 0; i < 2; i++)
#pragma unroll
          for (int j = 0; j < 4; j++)
            s[i][j] = __builtin_amdgcn_mfma_f32_16x16x32_bf16(aq[i][dk], bk[j], s[i][j], 0, 0, 0);
      }

      // scale + causal mask
      const bool masked_tile = (kk0 + 63 > q0 + rb);
#pragma unroll
      for (int i = 0; i < 2; i++)
#pragma unroll
        for (int j = 0; j < 4; j++)
#pragma unroll
          for (int r = 0; r < 4; r++) {
            float v = s[i][j][r] * scale;
            if (masked_tile) {
              int rg = q0 + rb + i * 16 + quad * 4 + r;
              int cg = kk0 + j * 16 + l16;
              if (cg > rg) v = NEG;
            }
            s[i][j][r] = v;
          }

      // wave-local online softmax; write P into private LDS (A-layout swizzle)
#pragma unroll
      for (int i = 0; i < 2; i++)
#pragma unroll
        for (int r = 0; r < 4; r++) {
          float mx = fmaxf(fmaxf(s[i][0][r], s[i][1][r]), fmaxf(s[i][2][r], s[i][3][r]));
#pragma unroll
          for (int t = 1; t < 16; t <<= 1) mx = fmaxf(mx, __shfl_xor(mx, t, 64));
          float mo = m_reg[i][r];
          float mn = fmaxf(mo, mx);
          float alpha = __expf(mo - mn);
          int row = i * 16 + quad * 4 + r;
          float rs = 0.0f;
#pragma unroll
          for (int j = 0; j < 4; j++) {
            float p = __expf(s[i][j][r] - mn);
            rs += p;
            int col = j * 16 + l16;
            Ps[pbase + (row * 8 + ((col >> 3) ^ (row & 7))) * 8 + (col & 7)] = (bf16)p;
          }
#pragma unroll
          for (int t = 1; t < 16; t <<= 1) rs += __shfl_xor(rs, t, 64);
          l_reg[i][r] = l_reg[i][r] * alpha + rs;
          m_reg[i][r] = mn;
#pragma unroll
          for (int j = 0; j < 8; j++) o[i][j][r] *= alpha;
        }

      // O += P @ V  (P private-wave A-operand; V^T B-operand; lgkmcnt only)
#pragma unroll
      for (int kkt = 0; kkt < 2; kkt++) {
        bf16x8 ap[2], bv[8];
#pragma unroll
        for (int i = 0; i < 2; i++) {
          int row = i * 16 + l16;
          ap[i] = *(const bf16x8*)&Ps[pbase + (row * 8 + ((kkt * 4 + quad) ^ (row & 7))) * 8];
        }
#pragma unroll
        for (int j = 0; j < 8; j++) {
          int row = j * 16 + l16;   // d index
          bv[j] = *(const bf16x8*)&Vs[(row * 8 + ((kkt * 4 + quad) ^ (row & 7))) * 8];
        }
#pragma unroll
        for (int i = 0; i < 2; i++)
#pragma unroll
          for (int j = 0; j < 8; j++)
            o[i][j] = __builtin_amdgcn_mfma_f32_16x16x32_bf16(ap[i], bv[j], o[i][j], 0, 0, 0);
      }
    }
    __syncthreads();   // B2: all waves done with Ks/Vs; safe to restage
  }

  // epilogue: O /= l, store bf16 (b, s, h, d) — in-place over own Q region
#pragma unroll
  for (int i = 0; i < 2; i++)
#pragma unroll
    for (int r = 0; r < 4; r++) {
      int row = rb + i * 16 + quad * 4 + r;
      float l = l_reg[i][r];
      float inv = (l > 0.0f) ? 1.0f / l : 0.0f;
      size_t base = ((size_t)(b * 2048 + q0 + row)) * 2048 + h * 128;
#pragma unroll
      for (int j = 0; j < 8; j++)
        AO[base + j * 16 + l16] = (bf16)(o[i][j][r] * inv);
    }
}

// ---------------------------------------------------------------------------
// Memory plan.  Inputs/outputs are fp32 (confirmed round 4).
//   d_ws  (>=32 MB known-safe): Qg/AO @0 (32 MB, in-place);
//         if ws_size >= 40.25 MB: wo_b @32M (8 MB) + ob_b @40M (4 KB)
//   d_out (64 MB fp32, dead until O-proj): Xb @0 (32 MB), Kg @32M (2 MB),
//         Vtg @34M (2 MB), wq_b @36M (8 MB), wkv_b @44M (1 MB),
//         qb_b @45M (4 KB), kvb_b @45M+4K (512 B)
// Order: cvt -> Q-proj -> KV-proj -> attention -> O-proj (overwrites d_out).
// ---------------------------------------------------------------------------
extern "C" void kernel_launch(void* const* d_in, const int* in_sizes, int n_in,
                              void* d_out, int out_size, void* d_ws, size_t ws_size,
                              hipStream_t stream)
{
  const float* X   = (const float*)d_in[0];
  const float* q_w = (const float*)d_in[1];
  const float* q_b = (const float*)d_in[2];
  const float* k_w = (const float*)d_in[3];
  const float* k_b = (const float*)d_in[4];
  const float* v_w = (const float*)d_in[5];
  const float* v_b = (const float*)d_in[6];
  const float* o_w = (const float*)d_in[7];
  const float* o_b = (const float*)d_in[8];

  char* outc = (char*)d_out;
  bf16* Xb    = (bf16*)(outc);                       // 8192 x 2048
  bf16* Kg    = (bf16*)(outc + 33554432);            // 8192 x 128 (b,s,d)
  bf16* Vtg   = (bf16*)(outc + 35651584);            // 4 x 128 x 2048 V^T
  bf16* wq_b  = (bf16*)(outc + 37748736);            // 2048 x 2048
  bf16* wkv_b = (bf16*)(outc + 46137344);            // 256 x 2048 (K rows 0-127, V 128-255)
  bf16* qb_b  = (bf16*)(outc + 47185920);            // 2048
  bf16* kvb_b = (bf16*)(outc + 47190016);            // 256

  bf16* Qg = (bf16*)d_ws;                            // 8192 x 2048; AO in-place
  bf16* AO = Qg;

  const bool big_ws = ws_size >= (size_t)(33554432 + 8388608 + 8192);
  bf16* wo_b = big_ws ? (bf16*)((char*)d_ws + 33554432) : nullptr;
  bf16* ob_b = big_ws ? (bf16*)((char*)d_ws + 41943040) : nullptr;

  CvtSegs segs;
  int n = 0;
  segs.src[n] = X;   segs.dst[n] = Xb;            segs.cnt[n] = 16777216; n++;
  segs.src[n] = q_w; segs.dst[n] = wq_b;          segs.cnt[n] = 4194304;  n++;
  segs.src[n] = k_w; segs.dst[n] = wkv_b;         segs.cnt[n] = 262144;   n++;
  segs.src[n] = v_w; segs.dst[n] = wkv_b + 262144; segs.cnt[n] = 262144;  n++;
  segs.src[n] = q_b; segs.dst[n] = qb_b;          segs.cnt[n] = 2048;     n++;
  segs.src[n] = k_b; segs.dst[n] = kvb_b;         segs.cnt[n] = 128;      n++;
  segs.src[n] = v_b; segs.dst[n] = kvb_b + 128;   segs.cnt[n] = 128;      n++;
  if (big_ws) {
    segs.src[n] = o_w; segs.dst[n] = wo_b;        segs.cnt[n] = 4194304;  n++;
    segs.src[n] = o_b; segs.dst[n] = ob_b;        segs.cnt[n] = 2048;     n++;
  }
  segs.n = n;

  dim3 blk(256);
  cvt_kernel<<<dim3(1024), blk, 0, stream>>>(segs);
  gemm_bt<<<dim3(64, 16), blk, 0, stream>>>(Xb, wq_b, qb_b, Qg, 8192, 2048, 2048, 0, 0, 0);
  gemm_bt<<<dim3(64, 2),  blk, 0, stream>>>(Xb, wkv_b, kvb_b, Kg, 8192, 256, 2048, 0, 0, 3);
  mqa_attn<<<dim3(16, 64), blk, 0, stream>>>(Qg, Kg, Vtg, AO);
  if (big_ws)
    gemm_bt<<<dim3(64, 16), blk, 0, stream>>>(AO, wo_b, ob_b, d_out, 8192, 2048, 2048, 0, 0, 2);
  else
    gemm_bt<<<dim3(64, 16), blk, 0, stream>>>(AO, o_w, o_b, d_out, 8192, 2048, 2048, 1, 1, 2);
}